// Round 9
// baseline (158.401 us; speedup 1.0000x reference)
//
#include <hip/hip_runtime.h>
#include <hip/hip_bf16.h>

#define D 512
#define TILE 128
#define NT 64                 // 8192 / TILE
#define NBLK (NT*(NT+1)/2)    // 2080 triangular blocks (2080 = 8*260)
#define XCHUNK (NBLK/8)       // 260 blocks per XCD chunk

typedef __attribute__((ext_vector_type(8))) short bf16x8;
typedef __attribute__((ext_vector_type(4))) float f32x4;

__device__ inline unsigned short f2bf(float x) {
    __hip_bfloat16 h = __float2bfloat16(x);
    return __builtin_bit_cast(unsigned short, h);
}

// Kernel A: row L2-norms, normalized bf16 matrix Yn[2N][D], pos[i]=exp(2*cos(y_i,yh_i))
__global__ __launch_bounds__(128) void prep_kernel(const float* __restrict__ y,
                                                   const float* __restrict__ yh,
                                                   unsigned short* __restrict__ Yn,
                                                   float* __restrict__ pos, int N) {
    const int i = blockIdx.x;
    const int t = threadIdx.x;  // 0..127, each owns one float4 (4 elems) of the 512
    const float4 a = ((const float4*)(y + (size_t)i * D))[t];
    const float4 b = ((const float4*)(yh + (size_t)i * D))[t];
    float sy = a.x*a.x + a.y*a.y + a.z*a.z + a.w*a.w;
    float sh = b.x*b.x + b.y*b.y + b.z*b.z + b.w*b.w;
    float sd = a.x*b.x + a.y*b.y + a.z*b.z + a.w*b.w;
    #pragma unroll
    for (int o = 32; o > 0; o >>= 1) {
        sy += __shfl_xor(sy, o);
        sh += __shfl_xor(sh, o);
        sd += __shfl_xor(sd, o);
    }
    __shared__ float red[3][2];
    const int wv = t >> 6;
    if ((t & 63) == 0) { red[0][wv] = sy; red[1][wv] = sh; red[2][wv] = sd; }
    __syncthreads();
    sy = red[0][0] + red[0][1];
    sh = red[1][0] + red[1][1];
    sd = red[2][0] + red[2][1];
    const float ny = sqrtf(sy), nh = sqrtf(sh);
    const float ry = 1.f / fmaxf(ny, 1e-12f), rh = 1.f / fmaxf(nh, 1e-12f);
    ushort4 oa, ob;
    oa.x = f2bf(a.x * ry); oa.y = f2bf(a.y * ry); oa.z = f2bf(a.z * ry); oa.w = f2bf(a.w * ry);
    ob.x = f2bf(b.x * rh); ob.y = f2bf(b.y * rh); ob.z = f2bf(b.z * rh); ob.w = f2bf(b.w * rh);
    ((ushort4*)(Yn + (size_t)i * D))[t] = oa;
    ((ushort4*)(Yn + (size_t)(i + N) * D))[t] = ob;
    if (t == 0) {
        const float cs = sd / (fmaxf(ny, 1e-8f) * fmaxf(nh, 1e-8f));
        pos[i] = __expf(2.f * cs);
    }
}

// Kernel B: neg[i] += sum_j exp(2 * Yn_i . Yn_j), diagonal masked.
// BARRIER-FREE: no LDS. Each wave loads its MFMA fragments directly from
// global (Yn is 8 MB, L2/L3-resident). A fragment load = 16 rows x one full
// 64B line -> line-granular, no over-fetch. Waves are fully independent;
// the compiler pipelines the load stream with counted vmcnt. Triangular
// grid + XCD-chunked remap for L2 panel locality; mirrored col sums.
__global__ __launch_bounds__(256, 4) void simgemm_kernel(const unsigned short* __restrict__ Yn,
                                                         float* __restrict__ neg) {
    // XCD-aware remap (bijective: NBLK % 8 == 0), then triangular decode
    const int t0 = blockIdx.x;
    const int t = (t0 & 7) * XCHUNK + (t0 >> 3);
    int bx = (int)((sqrtf(8.f * (float)t + 1.f) - 1.f) * 0.5f);
    while ((bx + 1) * (bx + 2) / 2 <= t) ++bx;
    while (bx * (bx + 1) / 2 > t) --bx;
    const int by = t - bx * (bx + 1) / 2;

    const int tid = threadIdx.x;
    const int lane = tid & 63;
    const int w = tid >> 6;
    const int wm = (w >> 1) * 64, wn = (w & 1) * 64;   // wave's 64x64 quadrant
    const int fr = lane & 15;    // A-row / B-col within 16x16 frag
    const int fq = lane >> 4;    // k-chunk (inputs) / row-quad (output)
    const int rowA0 = by * TILE, rowB0 = bx * TILE;

    f32x4 acc[4][4] = {};

    // per-lane fragment base pointers (16B aligned: row*1024B + fq*16B)
    const unsigned short* pA = Yn + (size_t)(rowA0 + wm + fr) * D + fq * 8;
    const unsigned short* pB = Yn + (size_t)(rowB0 + wn + fr) * D + fq * 8;

    #pragma unroll 2
    for (int kk = 0; kk < D; kk += 32) {
        bf16x8 af[4], bfr[4];
        #pragma unroll
        for (int m = 0; m < 4; ++m) af[m] = *(const bf16x8*)(pA + (size_t)m * 16 * D + kk);
        #pragma unroll
        for (int n = 0; n < 4; ++n) bfr[n] = *(const bf16x8*)(pB + (size_t)n * 16 * D + kk);
        #pragma unroll
        for (int m = 0; m < 4; ++m)
            #pragma unroll
            for (int n = 0; n < 4; ++n)
                acc[m][n] = __builtin_amdgcn_mfma_f32_16x16x32_bf16(af[m], bfr[n], acc[m][n], 0, 0, 0);
    }

    const bool diagblk = (bx == by);
    // exp transform in-place (+ exact diagonal mask)
    #pragma unroll
    for (int m = 0; m < 4; ++m)
        #pragma unroll
        for (int n = 0; n < 4; ++n)
            #pragma unroll
            for (int r = 0; r < 4; ++r) {
                const float e = __expf(2.f * acc[m][n][r]);
                const bool diag = diagblk && (wm + m * 16 + fq * 4 + r) == (wn + n * 16 + fr);
                acc[m][n][r] = diag ? 0.f : e;
            }
    // row sums: reduce over n-frags then over the 16 col-lanes
    #pragma unroll
    for (int m = 0; m < 4; ++m)
        #pragma unroll
        for (int r = 0; r < 4; ++r) {
            float v = acc[m][0][r] + acc[m][1][r] + acc[m][2][r] + acc[m][3][r];
            v += __shfl_xor(v, 1);
            v += __shfl_xor(v, 2);
            v += __shfl_xor(v, 4);
            v += __shfl_xor(v, 8);
            if (fr == 0) atomicAdd(&neg[rowA0 + wm + m * 16 + fq * 4 + r], v);
        }
    // mirrored column sums for off-diagonal blocks
    if (!diagblk) {
        #pragma unroll
        for (int n = 0; n < 4; ++n) {
            float v = 0.f;
            #pragma unroll
            for (int m = 0; m < 4; ++m)
                #pragma unroll
                for (int r = 0; r < 4; ++r) v += acc[m][n][r];
            v += __shfl_xor(v, 16);
            v += __shfl_xor(v, 32);
            if (fq == 0) atomicAdd(&neg[rowB0 + wn + n * 16 + fr], v);
        }
    }
}

// Kernel C: loss = log(2N) - log( sum_i pos[i] * (1/neg[i] + 1/neg[i+N]) )
__global__ __launch_bounds__(1024) void finish_kernel(const float* __restrict__ pos,
                                                      const float* __restrict__ neg,
                                                      float* __restrict__ out, int N) {
    float s = 0.f;
    for (int i = threadIdx.x; i < N; i += 1024)
        s += pos[i] * (1.f / neg[i] + 1.f / neg[i + N]);
    #pragma unroll
    for (int o = 32; o > 0; o >>= 1) s += __shfl_xor(s, o);
    __shared__ float red[16];
    const int wv = threadIdx.x >> 6;
    if ((threadIdx.x & 63) == 0) red[wv] = s;
    __syncthreads();
    if (threadIdx.x == 0) {
        float tot = 0.f;
        #pragma unroll
        for (int k = 0; k < 16; ++k) tot += red[k];
        out[0] = logf(2.f * (float)N) - logf(tot);
    }
}

extern "C" void kernel_launch(void* const* d_in, const int* in_sizes, int n_in,
                              void* d_out, int out_size, void* d_ws, size_t ws_size,
                              hipStream_t stream) {
    const float* y  = (const float*)d_in[0];
    const float* yh = (const float*)d_in[1];
    const int N  = in_sizes[0] / D;   // 4096
    const int N2 = 2 * N;             // 8192

    unsigned short* Yn = (unsigned short*)d_ws;                 // [2N][D] bf16, 8 MB
    const size_t yn_bytes = (size_t)N2 * D * sizeof(unsigned short);
    float* neg = (float*)((char*)d_ws + yn_bytes);              // [2N]
    float* pos = neg + N2;                                      // [N]
    float* out = (float*)d_out;

    hipMemsetAsync(neg, 0, N2 * sizeof(float), stream);
    prep_kernel<<<N, 128, 0, stream>>>(y, yh, Yn, pos, N);
    simgemm_kernel<<<NBLK, 256, 0, stream>>>(Yn, neg);
    finish_kernel<<<1, 1024, 0, stream>>>(pos, neg, out, N);
}

// Round 10
// 83.299 us; speedup vs baseline: 1.9016x; 1.9016x over previous
//
#include <hip/hip_runtime.h>
#include <hip/hip_bf16.h>

#define D 512
#define BM 256
#define BK 64
#define NT 32                 // 8192 / 256
#define NBLK (NT*(NT+1)/2)    // 528 triangular blocks (528 = 8*66)
#define XCHUNK (NBLK/8)       // 66 blocks per XCD chunk

typedef __attribute__((ext_vector_type(8))) short bf16x8;
typedef __attribute__((ext_vector_type(4))) float f32x4;

__device__ inline unsigned short f2bf(float x) {
    __hip_bfloat16 h = __float2bfloat16(x);
    return __builtin_bit_cast(unsigned short, h);
}

// async global -> LDS, 16B per lane; LDS dest is wave-uniform base + lane*16
__device__ inline void gload16(const unsigned short* g, unsigned short* l) {
    __builtin_amdgcn_global_load_lds(
        (const __attribute__((address_space(1))) unsigned int*)g,
        (__attribute__((address_space(3))) unsigned int*)l,
        16, 0, 0);
}

// Kernel A: row L2-norms, normalized bf16 matrix Yn[2N][D], pos[i]=exp(2*cos(y_i,yh_i))
__global__ __launch_bounds__(128) void prep_kernel(const float* __restrict__ y,
                                                   const float* __restrict__ yh,
                                                   unsigned short* __restrict__ Yn,
                                                   float* __restrict__ pos, int N) {
    const int i = blockIdx.x;
    const int t = threadIdx.x;  // 0..127, each owns one float4 (4 elems) of the 512
    const float4 a = ((const float4*)(y + (size_t)i * D))[t];
    const float4 b = ((const float4*)(yh + (size_t)i * D))[t];
    float sy = a.x*a.x + a.y*a.y + a.z*a.z + a.w*a.w;
    float sh = b.x*b.x + b.y*b.y + b.z*b.z + b.w*b.w;
    float sd = a.x*b.x + a.y*b.y + a.z*b.z + a.w*b.w;
    #pragma unroll
    for (int o = 32; o > 0; o >>= 1) {
        sy += __shfl_xor(sy, o);
        sh += __shfl_xor(sh, o);
        sd += __shfl_xor(sd, o);
    }
    __shared__ float red[3][2];
    const int wv = t >> 6;
    if ((t & 63) == 0) { red[0][wv] = sy; red[1][wv] = sh; red[2][wv] = sd; }
    __syncthreads();
    sy = red[0][0] + red[0][1];
    sh = red[1][0] + red[1][1];
    sd = red[2][0] + red[2][1];
    const float ny = sqrtf(sy), nh = sqrtf(sh);
    const float ry = 1.f / fmaxf(ny, 1e-12f), rh = 1.f / fmaxf(nh, 1e-12f);
    ushort4 oa, ob;
    oa.x = f2bf(a.x * ry); oa.y = f2bf(a.y * ry); oa.z = f2bf(a.z * ry); oa.w = f2bf(a.w * ry);
    ob.x = f2bf(b.x * rh); ob.y = f2bf(b.y * rh); ob.z = f2bf(b.z * rh); ob.w = f2bf(b.w * rh);
    ((ushort4*)(Yn + (size_t)i * D))[t] = oa;
    ((ushort4*)(Yn + (size_t)(i + N) * D))[t] = ob;
    if (t == 0) {
        const float cs = sd / (fmaxf(ny, 1e-8f) * fmaxf(nh, 1e-8f));
        pos[i] = __expf(2.f * cs);
    }
}

// Kernel B: neg[i] += sum_j exp(2 * Yn_i . Yn_j), diagonal masked.
// 256x256 tile, 8 waves (2M x 4N, per-wave 128x64), BK=64, 2-phase double
// buffer (R5 structure scaled up): STAGE(next) -> ds_read+MFMA(cur) -> one
// __syncthreads per K-step. global_load_lds w16 with linear LDS dest;
// source pre-swizzled chunk^=(row&7), same XOR on ds_read (verified pair).
// Triangular grid (bx>=by) + bijective XCD-chunked remap; mirrored col sums.
__global__ __launch_bounds__(512, 2) void simgemm_kernel(const unsigned short* __restrict__ Yn,
                                                         float* __restrict__ neg) {
    // XCD-aware remap (bijective: NBLK % 8 == 0), then triangular decode
    const int t0 = blockIdx.x;
    const int t = (t0 & 7) * XCHUNK + (t0 >> 3);
    int bx = (int)((sqrtf(8.f * (float)t + 1.f) - 1.f) * 0.5f);
    while ((bx + 1) * (bx + 2) / 2 <= t) ++bx;
    while (bx * (bx + 1) / 2 > t) --bx;
    const int by = t - bx * (bx + 1) / 2;

    __shared__ unsigned short As[2][BM * BK];   // 2 x 32 KB
    __shared__ unsigned short Bs[2][BM * BK];   // 2 x 32 KB  (128 KB total)
    const int tid = threadIdx.x;
    const int lane = tid & 63;
    const int w = tid >> 6;                     // 0..7
    const int wm = (w >> 2) * 128;              // 0 / 128
    const int wn = (w & 3) * 64;                // 0 / 64 / 128 / 192
    const int fr = lane & 15;    // A-row / B-col within 16x16 frag
    const int fq = lane >> 4;    // k-chunk (inputs) / row-quad (output)
    const int rowA0 = by * BM, rowB0 = bx * BM;

    f32x4 acc[8][4] = {};

    // staging: thread covers rows srow + p*64 (p=0..3), 16B chunk pre-swizzled
    const int srow = tid >> 3;                                  // 0..63
    const int scol = (((tid & 7) ^ ((tid >> 3) & 7)) << 3);     // source col (elems)
    const int ldsoff = w * 512;                                 // wave-uniform elems

    const unsigned short* gA = Yn + (size_t)(rowA0 + srow) * D + scol;
    const unsigned short* gB = Yn + (size_t)(rowB0 + srow) * D + scol;

    auto STAGE = [&](int buf, int k0) {
        #pragma unroll
        for (int p = 0; p < 4; ++p) {
            gload16(gA + (size_t)p * 64 * D + k0, &As[buf][p * 4096 + ldsoff]);
            gload16(gB + (size_t)p * 64 * D + k0, &Bs[buf][p * 4096 + ldsoff]);
        }
    };

    STAGE(0, 0);
    __syncthreads();               // drain prologue stage
    int cur = 0;
    for (int kt = 0; kt < D / BK; ++kt) {
        if (kt < D / BK - 1) STAGE(cur ^ 1, (kt + 1) * BK);    // issue next-tile loads first
        #pragma unroll
        for (int kk = 0; kk < BK; kk += 32) {
            bf16x8 af[8], bfr[4];
            #pragma unroll
            for (int m = 0; m < 8; ++m) {
                const int row = wm + m * 16 + fr;
                const int koff = ((((kk >> 3) + fq) ^ (row & 7)) << 3);
                af[m] = *(bf16x8*)&As[cur][row * BK + koff];
            }
            #pragma unroll
            for (int n = 0; n < 4; ++n) {
                const int row = wn + n * 16 + fr;
                const int koff = ((((kk >> 3) + fq) ^ (row & 7)) << 3);
                bfr[n] = *(bf16x8*)&Bs[cur][row * BK + koff];
            }
            #pragma unroll
            for (int m = 0; m < 8; ++m)
                #pragma unroll
                for (int n = 0; n < 4; ++n)
                    acc[m][n] = __builtin_amdgcn_mfma_f32_16x16x32_bf16(af[m], bfr[n], acc[m][n], 0, 0, 0);
        }
        __syncthreads();           // drains vmcnt (next stage) + lgkm, barrier
        cur ^= 1;
    }

    const bool diagblk = (bx == by);
    // exp transform in-place (+ exact diagonal mask)
    #pragma unroll
    for (int m = 0; m < 8; ++m)
        #pragma unroll
        for (int n = 0; n < 4; ++n)
            #pragma unroll
            for (int r = 0; r < 4; ++r) {
                const float e = __expf(2.f * acc[m][n][r]);
                const bool diag = diagblk && (wm + m * 16 + fq * 4 + r) == (wn + n * 16 + fr);
                acc[m][n][r] = diag ? 0.f : e;
            }
    // row sums: reduce over n-frags then over the 16 col-lanes
    #pragma unroll
    for (int m = 0; m < 8; ++m)
        #pragma unroll
        for (int r = 0; r < 4; ++r) {
            float v = acc[m][0][r] + acc[m][1][r] + acc[m][2][r] + acc[m][3][r];
            v += __shfl_xor(v, 1);
            v += __shfl_xor(v, 2);
            v += __shfl_xor(v, 4);
            v += __shfl_xor(v, 8);
            if (fr == 0) atomicAdd(&neg[rowA0 + wm + m * 16 + fq * 4 + r], v);
        }
    // mirrored column sums for off-diagonal blocks
    if (!diagblk) {
        #pragma unroll
        for (int n = 0; n < 4; ++n) {
            float v = 0.f;
            #pragma unroll
            for (int m = 0; m < 8; ++m)
                #pragma unroll
                for (int r = 0; r < 4; ++r) v += acc[m][n][r];
            v += __shfl_xor(v, 16);
            v += __shfl_xor(v, 32);
            if (fq == 0) atomicAdd(&neg[rowB0 + wn + n * 16 + fr], v);
        }
    }
}

// Kernel C: loss = log(2N) - log( sum_i pos[i] * (1/neg[i] + 1/neg[i+N]) )
__global__ __launch_bounds__(1024) void finish_kernel(const float* __restrict__ pos,
                                                      const float* __restrict__ neg,
                                                      float* __restrict__ out, int N) {
    float s = 0.f;
    for (int i = threadIdx.x; i < N; i += 1024)
        s += pos[i] * (1.f / neg[i] + 1.f / neg[i + N]);
    #pragma unroll
    for (int o = 32; o > 0; o >>= 1) s += __shfl_xor(s, o);
    __shared__ float red[16];
    const int wv = threadIdx.x >> 6;
    if ((threadIdx.x & 63) == 0) red[wv] = s;
    __syncthreads();
    if (threadIdx.x == 0) {
        float tot = 0.f;
        #pragma unroll
        for (int k = 0; k < 16; ++k) tot += red[k];
        out[0] = logf(2.f * (float)N) - logf(tot);
    }
}

extern "C" void kernel_launch(void* const* d_in, const int* in_sizes, int n_in,
                              void* d_out, int out_size, void* d_ws, size_t ws_size,
                              hipStream_t stream) {
    const float* y  = (const float*)d_in[0];
    const float* yh = (const float*)d_in[1];
    const int N  = in_sizes[0] / D;   // 4096
    const int N2 = 2 * N;             // 8192

    unsigned short* Yn = (unsigned short*)d_ws;                 // [2N][D] bf16, 8 MB
    const size_t yn_bytes = (size_t)N2 * D * sizeof(unsigned short);
    float* neg = (float*)((char*)d_ws + yn_bytes);              // [2N]
    float* pos = neg + N2;                                      // [N]
    float* out = (float*)d_out;

    hipMemsetAsync(neg, 0, N2 * sizeof(float), stream);
    prep_kernel<<<N, 128, 0, stream>>>(y, yh, Yn, pos, N);
    simgemm_kernel<<<NBLK, 512, 0, stream>>>(Yn, neg);
    finish_kernel<<<1, 1024, 0, stream>>>(pos, neg, out, N);
}

// Round 11
// 82.350 us; speedup vs baseline: 1.9235x; 1.0115x over previous
//
#include <hip/hip_runtime.h>
#include <hip/hip_bf16.h>

#define D 512
#define BM 256
#define BK 64
#define NT 32                 // 8192 / 256
#define NBLK (NT*(NT+1)/2)    // 528 triangular blocks (528 = 8*66)
#define XCHUNK (NBLK/8)       // 66 blocks per XCD chunk

typedef __attribute__((ext_vector_type(8))) short bf16x8;
typedef __attribute__((ext_vector_type(4))) float f32x4;

__device__ inline unsigned short f2bf(float x) {
    __hip_bfloat16 h = __float2bfloat16(x);
    return __builtin_bit_cast(unsigned short, h);
}

// async global -> LDS, 16B per lane; LDS dest is wave-uniform base + lane*16
__device__ inline void gload16(const unsigned short* g, unsigned short* l) {
    __builtin_amdgcn_global_load_lds(
        (const __attribute__((address_space(1))) unsigned int*)g,
        (__attribute__((address_space(3))) unsigned int*)l,
        16, 0, 0);
}

// Kernel A: row L2-norms, normalized bf16 matrix Yn[2N][D], pos[i]=exp(2*cos(y_i,yh_i))
__global__ __launch_bounds__(128) void prep_kernel(const float* __restrict__ y,
                                                   const float* __restrict__ yh,
                                                   unsigned short* __restrict__ Yn,
                                                   float* __restrict__ pos, int N) {
    const int i = blockIdx.x;
    const int t = threadIdx.x;
    const float4 a = ((const float4*)(y + (size_t)i * D))[t];
    const float4 b = ((const float4*)(yh + (size_t)i * D))[t];
    float sy = a.x*a.x + a.y*a.y + a.z*a.z + a.w*a.w;
    float sh = b.x*b.x + b.y*b.y + b.z*b.z + b.w*b.w;
    float sd = a.x*b.x + a.y*b.y + a.z*b.z + a.w*b.w;
    #pragma unroll
    for (int o = 32; o > 0; o >>= 1) {
        sy += __shfl_xor(sy, o);
        sh += __shfl_xor(sh, o);
        sd += __shfl_xor(sd, o);
    }
    __shared__ float red[3][2];
    const int wv = t >> 6;
    if ((t & 63) == 0) { red[0][wv] = sy; red[1][wv] = sh; red[2][wv] = sd; }
    __syncthreads();
    sy = red[0][0] + red[0][1];
    sh = red[1][0] + red[1][1];
    sd = red[2][0] + red[2][1];
    const float ny = sqrtf(sy), nh = sqrtf(sh);
    const float ry = 1.f / fmaxf(ny, 1e-12f), rh = 1.f / fmaxf(nh, 1e-12f);
    ushort4 oa, ob;
    oa.x = f2bf(a.x * ry); oa.y = f2bf(a.y * ry); oa.z = f2bf(a.z * ry); oa.w = f2bf(a.w * ry);
    ob.x = f2bf(b.x * rh); ob.y = f2bf(b.y * rh); ob.z = f2bf(b.z * rh); ob.w = f2bf(b.w * rh);
    ((ushort4*)(Yn + (size_t)i * D))[t] = oa;
    ((ushort4*)(Yn + (size_t)(i + N) * D))[t] = ob;
    if (t == 0) {
        const float cs = sd / (fmaxf(ny, 1e-8f) * fmaxf(nh, 1e-8f));
        pos[i] = __expf(2.f * cs);
    }
}

// Kernel B: 256x256 tile, 8 waves, 8-phase schedule (4 phases/K-tile, 2 kk x
// 2 m-half quadrants), raw s_barrier + counted vmcnt(2) (never 0 in loop).
// Staging in quarter-tiles (64 rows = 1 gload16 issue): region-safe schedule
//   P1: A-q1,q3(t+1)  P2: B-q0,q1(t+1)  P3: B-q2,q3(t+1)  P4: A-q0,q2(t+2)
// (A-mhi of next buf free after prev P4; B free after prev P3; A-mlo of cur
// buf free after cur P3.) vmcnt(2) at P4 completes tile t+1, keeps t+2's
// first 2 quarters in flight. Swizzle pair as verified (chunk^=(row&7)).
__global__ __launch_bounds__(512, 2) void simgemm_kernel(const unsigned short* __restrict__ Yn,
                                                         float* __restrict__ neg) {
    const int t0 = blockIdx.x;
    const int t = (t0 & 7) * XCHUNK + (t0 >> 3);
    int bx = (int)((sqrtf(8.f * (float)t + 1.f) - 1.f) * 0.5f);
    while ((bx + 1) * (bx + 2) / 2 <= t) ++bx;
    while (bx * (bx + 1) / 2 > t) --bx;
    const int by = t - bx * (bx + 1) / 2;

    __shared__ unsigned short As[2][BM * BK];   // 2 x 32 KB
    __shared__ unsigned short Bs[2][BM * BK];   // 2 x 32 KB
    const int tid = threadIdx.x;
    const int lane = tid & 63;
    const int w = tid >> 6;                     // 0..7
    const int wm = (w >> 2) * 128;              // 0 / 128
    const int wn = (w & 3) * 64;                // 0 / 64 / 128 / 192
    const int fr = lane & 15;
    const int fq = lane >> 4;
    const int rowA0 = by * BM, rowB0 = bx * BM;

    f32x4 acc[8][4] = {};

    const int srow = tid >> 3;                                  // 0..63
    const int scol = (((tid & 7) ^ ((tid >> 3) & 7)) << 3);     // pre-swizzled source col
    const int ldsoff = w * 512;                                 // wave-uniform elems

    const unsigned short* gA = Yn + (size_t)(rowA0 + srow) * D + scol;
    const unsigned short* gB = Yn + (size_t)(rowB0 + srow) * D + scol;

    auto SQA = [&](int buf, int k0, int q) {
        gload16(gA + (size_t)q * 64 * D + k0, &As[buf][q * 4096 + ldsoff]);
    };
    auto SQB = [&](int buf, int k0, int q) {
        gload16(gB + (size_t)q * 64 * D + k0, &Bs[buf][q * 4096 + ldsoff]);
    };
    auto ldA = [&](bf16x8* dst, int cur, int rbase, int kk) {
        #pragma unroll
        for (int m = 0; m < 4; ++m) {
            const int row = rbase + m * 16 + fr;
            const int koff = ((((kk >> 3) + fq) ^ (row & 7)) << 3);
            dst[m] = *(bf16x8*)&As[cur][row * BK + koff];
        }
    };
    auto ldB = [&](bf16x8* dst, int cur, int kk) {
        #pragma unroll
        for (int n = 0; n < 4; ++n) {
            const int row = wn + n * 16 + fr;
            const int koff = ((((kk >> 3) + fq) ^ (row & 7)) << 3);
            dst[n] = *(bf16x8*)&Bs[cur][row * BK + koff];
        }
    };

    // prologue: tile0 (8 quarters) + tile1 A-q0,q2 -> 10 in flight, keep 2
    #pragma unroll
    for (int q = 0; q < 4; ++q) { SQA(0, 0, q); SQB(0, 0, q); }
    SQA(1, BK, 0); SQA(1, BK, 2);
    asm volatile("s_waitcnt vmcnt(2)" ::: "memory");
    __builtin_amdgcn_s_barrier();

    for (int kt = 0; kt < 7; ++kt) {
        const int cur = kt & 1, nxt = cur ^ 1;
        const int k1 = (kt + 1) * BK;
        bf16x8 af[4], ag[4], b0[4], b1[4];
        // ---- P1: (kk0, mlo)
        ldA(af, cur, wm, 0);
        ldB(b0, cur, 0);
        SQA(nxt, k1, 1); SQA(nxt, k1, 3);
        __builtin_amdgcn_s_barrier();
        asm volatile("s_waitcnt lgkmcnt(0)" ::: "memory");
        __builtin_amdgcn_s_setprio(1);
        #pragma unroll
        for (int m = 0; m < 4; ++m)
            #pragma unroll
            for (int n = 0; n < 4; ++n)
                acc[m][n] = __builtin_amdgcn_mfma_f32_16x16x32_bf16(af[m], b0[n], acc[m][n], 0, 0, 0);
        __builtin_amdgcn_s_setprio(0);
        __builtin_amdgcn_s_barrier();
        // ---- P2: (kk0, mhi)
        ldA(ag, cur, wm + 64, 0);
        SQB(nxt, k1, 0); SQB(nxt, k1, 1);
        __builtin_amdgcn_s_barrier();
        asm volatile("s_waitcnt lgkmcnt(0)" ::: "memory");
        __builtin_amdgcn_s_setprio(1);
        #pragma unroll
        for (int m = 0; m < 4; ++m)
            #pragma unroll
            for (int n = 0; n < 4; ++n)
                acc[m + 4][n] = __builtin_amdgcn_mfma_f32_16x16x32_bf16(ag[m], b0[n], acc[m + 4][n], 0, 0, 0);
        __builtin_amdgcn_s_setprio(0);
        __builtin_amdgcn_s_barrier();
        // ---- P3: (kk1, mlo)
        ldA(af, cur, wm, 32);
        ldB(b1, cur, 32);
        SQB(nxt, k1, 2); SQB(nxt, k1, 3);
        __builtin_amdgcn_s_barrier();
        asm volatile("s_waitcnt lgkmcnt(0)" ::: "memory");
        __builtin_amdgcn_s_setprio(1);
        #pragma unroll
        for (int m = 0; m < 4; ++m)
            #pragma unroll
            for (int n = 0; n < 4; ++n)
                acc[m][n] = __builtin_amdgcn_mfma_f32_16x16x32_bf16(af[m], b1[n], acc[m][n], 0, 0, 0);
        __builtin_amdgcn_s_setprio(0);
        __builtin_amdgcn_s_barrier();
        // ---- P4: (kk1, mhi)
        ldA(ag, cur, wm + 64, 32);
        if (kt < 6) { SQA(cur, k1 + BK, 0); SQA(cur, k1 + BK, 2); }
        __builtin_amdgcn_s_barrier();
        asm volatile("s_waitcnt lgkmcnt(0)" ::: "memory");
        __builtin_amdgcn_s_setprio(1);
        #pragma unroll
        for (int m = 0; m < 4; ++m)
            #pragma unroll
            for (int n = 0; n < 4; ++n)
                acc[m + 4][n] = __builtin_amdgcn_mfma_f32_16x16x32_bf16(ag[m], b1[n], acc[m + 4][n], 0, 0, 0);
        __builtin_amdgcn_s_setprio(0);
        if (kt < 6) asm volatile("s_waitcnt vmcnt(2)" ::: "memory");
        else        asm volatile("s_waitcnt vmcnt(0)" ::: "memory");
        __builtin_amdgcn_s_barrier();
    }
    // ---- epilogue K-tile 7 (buf 1, fully resident, no staging/barriers)
    {
        #pragma unroll
        for (int kk = 0; kk < BK; kk += 32) {
            bf16x8 af[4], ag[4], bb[4];
            ldA(af, 1, wm, kk);
            ldA(ag, 1, wm + 64, kk);
            ldB(bb, 1, kk);
            #pragma unroll
            for (int m = 0; m < 4; ++m)
                #pragma unroll
                for (int n = 0; n < 4; ++n) {
                    acc[m][n]     = __builtin_amdgcn_mfma_f32_16x16x32_bf16(af[m], bb[n], acc[m][n], 0, 0, 0);
                    acc[m + 4][n] = __builtin_amdgcn_mfma_f32_16x16x32_bf16(ag[m], bb[n], acc[m + 4][n], 0, 0, 0);
                }
        }
    }

    const bool diagblk = (bx == by);
    #pragma unroll
    for (int m = 0; m < 8; ++m)
        #pragma unroll
        for (int n = 0; n < 4; ++n)
            #pragma unroll
            for (int r = 0; r < 4; ++r) {
                const float e = __expf(2.f * acc[m][n][r]);
                const bool diag = diagblk && (wm + m * 16 + fq * 4 + r) == (wn + n * 16 + fr);
                acc[m][n][r] = diag ? 0.f : e;
            }
    #pragma unroll
    for (int m = 0; m < 8; ++m)
        #pragma unroll
        for (int r = 0; r < 4; ++r) {
            float v = acc[m][0][r] + acc[m][1][r] + acc[m][2][r] + acc[m][3][r];
            v += __shfl_xor(v, 1);
            v += __shfl_xor(v, 2);
            v += __shfl_xor(v, 4);
            v += __shfl_xor(v, 8);
            if (fr == 0) atomicAdd(&neg[rowA0 + wm + m * 16 + fq * 4 + r], v);
        }
    if (!diagblk) {
        #pragma unroll
        for (int n = 0; n < 4; ++n) {
            float v = 0.f;
            #pragma unroll
            for (int m = 0; m < 8; ++m)
                #pragma unroll
                for (int r = 0; r < 4; ++r) v += acc[m][n][r];
            v += __shfl_xor(v, 16);
            v += __shfl_xor(v, 32);
            if (fq == 0) atomicAdd(&neg[rowB0 + wn + n * 16 + fr], v);
        }
    }
}

// Kernel C: loss = log(2N) - log( sum_i pos[i] * (1/neg[i] + 1/neg[i+N]) )
__global__ __launch_bounds__(1024) void finish_kernel(const float* __restrict__ pos,
                                                      const float* __restrict__ neg,
                                                      float* __restrict__ out, int N) {
    float s = 0.f;
    for (int i = threadIdx.x; i < N; i += 1024)
        s += pos[i] * (1.f / neg[i] + 1.f / neg[i + N]);
    #pragma unroll
    for (int o = 32; o > 0; o >>= 1) s += __shfl_xor(s, o);
    __shared__ float red[16];
    const int wv = threadIdx.x >> 6;
    if ((threadIdx.x & 63) == 0) red[wv] = s;
    __syncthreads();
    if (threadIdx.x == 0) {
        float tot = 0.f;
        #pragma unroll
        for (int k = 0; k < 16; ++k) tot += red[k];
        out[0] = logf(2.f * (float)N) - logf(tot);
    }
}

extern "C" void kernel_launch(void* const* d_in, const int* in_sizes, int n_in,
                              void* d_out, int out_size, void* d_ws, size_t ws_size,
                              hipStream_t stream) {
    const float* y  = (const float*)d_in[0];
    const float* yh = (const float*)d_in[1];
    const int N  = in_sizes[0] / D;   // 4096
    const int N2 = 2 * N;             // 8192

    unsigned short* Yn = (unsigned short*)d_ws;                 // [2N][D] bf16, 8 MB
    const size_t yn_bytes = (size_t)N2 * D * sizeof(unsigned short);
    float* neg = (float*)((char*)d_ws + yn_bytes);              // [2N]
    float* pos = neg + N2;                                      // [N]
    float* out = (float*)d_out;

    hipMemsetAsync(neg, 0, N2 * sizeof(float), stream);
    prep_kernel<<<N, 128, 0, stream>>>(y, yh, Yn, pos, N);
    simgemm_kernel<<<NBLK, 512, 0, stream>>>(Yn, neg);
    finish_kernel<<<1, 1024, 0, stream>>>(pos, neg, out, N);
}